// Round 1
// baseline (16961.093 us; speedup 1.0000x reference)
//
#include <hip/hip_runtime.h>

// Problem constants (fixed by the reference)
constexpr int N_  = 100000;
constexpr int E_  = 3200000;
constexpr int FIN = 16;
constexpr int H_  = 128;
constexpr int LAT = 64;
constexpr int L_  = 3;
constexpr int G_  = 1024;

// ---------------------------------------------------------------------------
// h = relu(x @ W_in + b_in)   x:[N,16] W:[16,128]
// block = 256 threads -> 2 nodes per block
// ---------------------------------------------------------------------------
__global__ __launch_bounds__(256) void k_input(const float* __restrict__ x,
                                               const float* __restrict__ Win,
                                               const float* __restrict__ bin,
                                               float* __restrict__ h) {
  __shared__ float Wl[FIN * H_];   // 8 KB
  __shared__ float xl[2 * FIN];
  const int tid = threadIdx.x;
  for (int i = tid; i < FIN * H_; i += 256) Wl[i] = Win[i];
  const int n0 = blockIdx.x * 2;
  if (tid < 2 * FIN) {
    const int nl = tid / FIN, k = tid % FIN;
    const int n = n0 + nl;
    xl[tid] = (n < N_) ? x[(size_t)n * FIN + k] : 0.f;
  }
  __syncthreads();
  const int nl = tid >> 7, c = tid & 127;
  const int n = n0 + nl;
  if (n < N_) {
    float acc = bin[c];
#pragma unroll
    for (int k = 0; k < FIN; ++k) acc += xl[nl * FIN + k] * Wl[k * H_ + c];
    h[(size_t)n * H_ + c] = fmaxf(acc, 0.f);
  }
}

// ---------------------------------------------------------------------------
// m = relu(h) @ W + b      [N,128] x [128,128]
// block = 512 threads -> 4 nodes per grid-stride step; W staged in 64 KB LDS.
// h row elements are wave-uniform loads (L1 broadcast).
// ---------------------------------------------------------------------------
__global__ __launch_bounds__(512) void k_msg(const float* __restrict__ h,
                                             const float* __restrict__ W,
                                             const float* __restrict__ b,
                                             float* __restrict__ m) {
  __shared__ float Wl[H_ * H_];    // 64 KB exactly
  const int tid = threadIdx.x;
  for (int i = tid; i < H_ * H_; i += 512) Wl[i] = W[i];
  const int nl = tid >> 7;          // 0..3
  const int c  = tid & 127;
  const float bc = b[c];
  const int nquads = N_ / 4;        // 25000
  __syncthreads();
  for (int p = blockIdx.x; p < nquads; p += gridDim.x) {
    const int n = p * 4 + nl;
    const float* hrow = h + (size_t)n * H_;
    float acc = bc;
#pragma unroll 8
    for (int k = 0; k < H_; ++k) {
      const float hk = fmaxf(hrow[k], 0.f);
      acc += hk * Wl[k * H_ + c];
    }
    m[(size_t)p * 512 + tid] = acc;
  }
}

// ---------------------------------------------------------------------------
// agg[dst] += m[src]  over E edges; 32 threads / edge, float4 gather,
// 4 scalar f32 HW atomics per thread.
// ---------------------------------------------------------------------------
__global__ __launch_bounds__(256) void k_scatter(const float* __restrict__ m,
                                                 float* __restrict__ agg,
                                                 const int* __restrict__ ei) {
  const int gid = blockIdx.x * blockDim.x + threadIdx.x;
  const int lane4 = (gid & 31) * 4;                 // channel offset 0..124
  const int estride = (gridDim.x * blockDim.x) >> 5;
  for (int e = gid >> 5; e < E_; e += estride) {
    const int src = ei[e];
    const int dst = ei[E_ + e];
    const float4 v = *reinterpret_cast<const float4*>(m + (size_t)src * H_ + lane4);
    float* p = agg + (size_t)dst * H_ + lane4;
    unsafeAtomicAdd(p + 0, v.x);
    unsafeAtomicAdd(p + 1, v.y);
    unsafeAtomicAdd(p + 2, v.z);
    unsafeAtomicAdd(p + 3, v.w);
  }
}

// ---------------------------------------------------------------------------
// ge[g] += relu(h[n])  with batch sorted: per-block running sum, flush on
// segment change. block = 128 threads (one per channel), CHUNK nodes/block.
// ---------------------------------------------------------------------------
constexpr int POOL_CHUNK = 128;
__global__ __launch_bounds__(128) void k_pool(const float* __restrict__ h,
                                              const int* __restrict__ batch,
                                              float* __restrict__ ge) {
  __shared__ int bl[POOL_CHUNK];
  const int tid = threadIdx.x;
  const int start = blockIdx.x * POOL_CHUNK;
  const int cnt = min(POOL_CHUNK, N_ - start);
  if (tid < cnt) bl[tid] = batch[start + tid];
  __syncthreads();
  float run = 0.f;
  int cur = bl[0];
  for (int i = 0; i < cnt; ++i) {
    const int bid = bl[i];
    const float v = fmaxf(h[(size_t)(start + i) * H_ + tid], 0.f);
    if (bid != cur) {
      unsafeAtomicAdd(&ge[(size_t)cur * H_ + tid], run);
      run = 0.f;
      cur = bid;
    }
    run += v;
  }
  unsafeAtomicAdd(&ge[(size_t)cur * H_ + tid], run);
}

// ---------------------------------------------------------------------------
// out = [ge @ W_mean + b_mean ; ge @ W_logvar + b_logvar]
// one block per graph; threads 0..63 -> mean, 64..127 -> logvar.
// ---------------------------------------------------------------------------
__global__ __launch_bounds__(128) void k_out(const float* __restrict__ ge,
                                             const float* __restrict__ Wm,
                                             const float* __restrict__ bm,
                                             const float* __restrict__ Wv,
                                             const float* __restrict__ bv,
                                             float* __restrict__ out) {
  __shared__ float gl[H_];
  const int g = blockIdx.x, tid = threadIdx.x;
  gl[tid] = ge[(size_t)g * H_ + tid];
  __syncthreads();
  const bool is_mean = (tid < LAT);
  const float* W = is_mean ? Wm : Wv;
  const float* bb = is_mean ? bm : bv;
  const int c = tid & 63;
  float acc = bb[c];
#pragma unroll 8
  for (int k = 0; k < H_; ++k) acc += gl[k] * W[k * LAT + c];
  const size_t off = is_mean ? 0 : (size_t)G_ * LAT;
  out[off + (size_t)g * LAT + c] = acc;
}

// ---------------------------------------------------------------------------
extern "C" void kernel_launch(void* const* d_in, const int* in_sizes, int n_in,
                              void* d_out, int out_size, void* d_ws, size_t ws_size,
                              hipStream_t stream) {
  const float* x     = (const float*)d_in[0];
  const int*   ei    = (const int*)d_in[1];   // [2,E] int32
  const int*   batch = (const int*)d_in[2];   // [N]  int32 (sorted)
  // d_in[3] = num_graphs scalar (== G_), unused
  const float* Win   = (const float*)d_in[4];
  const float* bin   = (const float*)d_in[5];
  const float* Wmsg  = (const float*)d_in[6];
  const float* bmsg  = (const float*)d_in[7];
  const float* Wmean = (const float*)d_in[8];
  const float* bmean = (const float*)d_in[9];
  const float* Wlv   = (const float*)d_in[10];
  const float* blv   = (const float*)d_in[11];
  float* out = (float*)d_out;

  float* bufA = (float*)d_ws;                       // [N,H] h / agg
  float* bufB = bufA + (size_t)N_ * H_;             // [N,H] m
  float* ge   = bufB + (size_t)N_ * H_;             // [G,H]

  // h = relu(x @ W_in + b_in)
  k_input<<<(N_ + 1) / 2, 256, 0, stream>>>(x, Win, bin, bufA);

  for (int l = 0; l < L_; ++l) {
    // m = relu(h) @ W_msg[l] + b_msg[l]
    k_msg<<<512, 512, 0, stream>>>(bufA, Wmsg + (size_t)l * H_ * H_,
                                   bmsg + (size_t)l * H_, bufB);
    // agg = 0; agg[dst] += m[src]
    hipMemsetAsync(bufA, 0, (size_t)N_ * H_ * sizeof(float), stream);
    k_scatter<<<2048, 256, 0, stream>>>(bufB, bufA, ei);
    // relu folded into the next consumer's loads
  }

  // graph pooling (relu folded into load)
  hipMemsetAsync(ge, 0, (size_t)G_ * H_ * sizeof(float), stream);
  k_pool<<<(N_ + POOL_CHUNK - 1) / POOL_CHUNK, 128, 0, stream>>>(bufA, batch, ge);

  // heads
  k_out<<<G_, 128, 0, stream>>>(ge, Wmean, bmean, Wlv, blv, out);
}

// Round 2
// 2287.635 us; speedup vs baseline: 7.4142x; 7.4142x over previous
//
#include <hip/hip_runtime.h>

// Problem constants (fixed by the reference)
constexpr int N_  = 100000;
constexpr int E_  = 3200000;
constexpr int FIN = 16;
constexpr int H_  = 128;
constexpr int LAT = 64;
constexpr int L_  = 3;
constexpr int G_  = 1024;

// ---------------------------------------------------------------------------
// h = relu(x @ W_in + b_in)   x:[N,16] W:[16,128]
// ---------------------------------------------------------------------------
__global__ __launch_bounds__(256) void k_input(const float* __restrict__ x,
                                               const float* __restrict__ Win,
                                               const float* __restrict__ bin,
                                               float* __restrict__ h) {
  __shared__ float Wl[FIN * H_];   // 8 KB
  __shared__ float xl[2 * FIN];
  const int tid = threadIdx.x;
  for (int i = tid; i < FIN * H_; i += 256) Wl[i] = Win[i];
  const int n0 = blockIdx.x * 2;
  if (tid < 2 * FIN) {
    const int nl = tid / FIN, k = tid % FIN;
    const int n = n0 + nl;
    xl[tid] = (n < N_) ? x[(size_t)n * FIN + k] : 0.f;
  }
  __syncthreads();
  const int nl = tid >> 7, c = tid & 127;
  const int n = n0 + nl;
  if (n < N_) {
    float acc = bin[c];
#pragma unroll
    for (int k = 0; k < FIN; ++k) acc += xl[nl * FIN + k] * Wl[k * H_ + c];
    h[(size_t)n * H_ + c] = fmaxf(acc, 0.f);
  }
}

// ---------------------------------------------------------------------------
// m = relu(h) @ W + b      [N,128] x [128,128]; W staged in 64 KB LDS.
// ---------------------------------------------------------------------------
__global__ __launch_bounds__(512) void k_msg(const float* __restrict__ h,
                                             const float* __restrict__ W,
                                             const float* __restrict__ b,
                                             float* __restrict__ m) {
  __shared__ float Wl[H_ * H_];    // 64 KB exactly
  const int tid = threadIdx.x;
  for (int i = tid; i < H_ * H_; i += 512) Wl[i] = W[i];
  const int nl = tid >> 7;          // 0..3
  const int c  = tid & 127;
  const float bc = b[c];
  const int nquads = N_ / 4;        // 25000
  __syncthreads();
  for (int p = blockIdx.x; p < nquads; p += gridDim.x) {
    const int n = p * 4 + nl;
    const float* hrow = h + (size_t)n * H_;
    float acc = bc;
#pragma unroll 8
    for (int k = 0; k < H_; ++k) {
      const float hk = fmaxf(hrow[k], 0.f);
      acc += hk * Wl[k * H_ + c];
    }
    m[(size_t)p * 512 + tid] = acc;
  }
}

// ---------------------------------------------------------------------------
// CSR build: counting sort of edges by dst (edge list is layer-invariant).
// ---------------------------------------------------------------------------
__global__ __launch_bounds__(256) void k_hist(const int* __restrict__ ei,
                                              int* __restrict__ deg) {
  const int gid = blockIdx.x * blockDim.x + threadIdx.x;
  const int stride = gridDim.x * blockDim.x;
  for (int e = gid; e < E_; e += stride) atomicAdd(&deg[ei[E_ + e]], 1);
}

// single-block exclusive scan: deg[0..N-1] -> rowptr[0..N]
__global__ __launch_bounds__(1024) void k_scan(const int* __restrict__ deg,
                                               int* __restrict__ rowptr) {
  __shared__ int sums[1024];
  const int t = threadIdx.x;
  constexpr int CH = (N_ + 1023) / 1024;   // 98
  const int beg = t * CH;
  const int end = min(beg + CH, N_);
  int s = 0;
  for (int i = beg; i < end; ++i) s += deg[i];
  sums[t] = s;
  __syncthreads();
  for (int off = 1; off < 1024; off <<= 1) {
    const int add = (t >= off) ? sums[t - off] : 0;
    __syncthreads();
    sums[t] += add;
    __syncthreads();
  }
  int run = (t == 0) ? 0 : sums[t - 1];
  for (int i = beg; i < end; ++i) { rowptr[i] = run; run += deg[i]; }
  if (beg < N_ && end == N_) rowptr[N_] = run;   // exactly one thread owns the tail
}

// fill[] must be zeroed before this; ssrc[rowptr[dst] + fill[dst]++] = src
__global__ __launch_bounds__(256) void k_fill(const int* __restrict__ ei,
                                              const int* __restrict__ rowptr,
                                              int* __restrict__ fill,
                                              int* __restrict__ ssrc) {
  const int gid = blockIdx.x * blockDim.x + threadIdx.x;
  const int stride = gridDim.x * blockDim.x;
  for (int e = gid; e < E_; e += stride) {
    const int src = ei[e];
    const int dst = ei[E_ + e];
    const int pos = rowptr[dst] + atomicAdd(&fill[dst], 1);
    ssrc[pos] = src;
  }
}

// ---------------------------------------------------------------------------
// h[n] = relu( sum_{e in CSR[n]} m[ssrc[e]] )   — gather, no atomics.
// 128 threads per node (one per channel); each edge iter = one coalesced
// 512 B row read. 2 nodes per 256-thread block.
// ---------------------------------------------------------------------------
__global__ __launch_bounds__(256) void k_gather(const float* __restrict__ m,
                                                const int* __restrict__ rowptr,
                                                const int* __restrict__ ssrc,
                                                float* __restrict__ h) {
  const int n = blockIdx.x * 2 + (threadIdx.x >> 7);
  const int c = threadIdx.x & 127;
  const int beg = rowptr[n], end = rowptr[n + 1];
  float acc = 0.f;
  int i = beg;
  for (; i + 1 < end; i += 2) {
    const int s0 = ssrc[i];
    const int s1 = ssrc[i + 1];
    const float v0 = m[(size_t)s0 * H_ + c];
    const float v1 = m[(size_t)s1 * H_ + c];
    acc += v0;
    acc += v1;
  }
  if (i < end) acc += m[(size_t)ssrc[i] * H_ + c];
  h[(size_t)n * H_ + c] = fmaxf(acc, 0.f);
}

// ---------------------------------------------------------------------------
// ge[g] += relu(h[n]) with batch sorted: per-block running sum, flush on change.
// ---------------------------------------------------------------------------
constexpr int POOL_CHUNK = 128;
__global__ __launch_bounds__(128) void k_pool(const float* __restrict__ h,
                                              const int* __restrict__ batch,
                                              float* __restrict__ ge) {
  __shared__ int bl[POOL_CHUNK];
  const int tid = threadIdx.x;
  const int start = blockIdx.x * POOL_CHUNK;
  const int cnt = min(POOL_CHUNK, N_ - start);
  if (tid < cnt) bl[tid] = batch[start + tid];
  __syncthreads();
  float run = 0.f;
  int cur = bl[0];
  for (int i = 0; i < cnt; ++i) {
    const int bid = bl[i];
    const float v = fmaxf(h[(size_t)(start + i) * H_ + tid], 0.f);
    if (bid != cur) {
      unsafeAtomicAdd(&ge[(size_t)cur * H_ + tid], run);
      run = 0.f;
      cur = bid;
    }
    run += v;
  }
  unsafeAtomicAdd(&ge[(size_t)cur * H_ + tid], run);
}

// ---------------------------------------------------------------------------
// out = [ge @ W_mean + b_mean ; ge @ W_logvar + b_logvar]
// ---------------------------------------------------------------------------
__global__ __launch_bounds__(128) void k_out(const float* __restrict__ ge,
                                             const float* __restrict__ Wm,
                                             const float* __restrict__ bm,
                                             const float* __restrict__ Wv,
                                             const float* __restrict__ bv,
                                             float* __restrict__ out) {
  __shared__ float gl[H_];
  const int g = blockIdx.x, tid = threadIdx.x;
  gl[tid] = ge[(size_t)g * H_ + tid];
  __syncthreads();
  const bool is_mean = (tid < LAT);
  const float* W = is_mean ? Wm : Wv;
  const float* bb = is_mean ? bm : bv;
  const int c = tid & 63;
  float acc = bb[c];
#pragma unroll 8
  for (int k = 0; k < H_; ++k) acc += gl[k] * W[k * LAT + c];
  const size_t off = is_mean ? 0 : (size_t)G_ * LAT;
  out[off + (size_t)g * LAT + c] = acc;
}

// ---------------------------------------------------------------------------
extern "C" void kernel_launch(void* const* d_in, const int* in_sizes, int n_in,
                              void* d_out, int out_size, void* d_ws, size_t ws_size,
                              hipStream_t stream) {
  const float* x     = (const float*)d_in[0];
  const int*   ei    = (const int*)d_in[1];   // [2,E] int32
  const int*   batch = (const int*)d_in[2];   // [N]  int32 (sorted)
  const float* Win   = (const float*)d_in[4];
  const float* bin   = (const float*)d_in[5];
  const float* Wmsg  = (const float*)d_in[6];
  const float* bmsg  = (const float*)d_in[7];
  const float* Wmean = (const float*)d_in[8];
  const float* bmean = (const float*)d_in[9];
  const float* Wlv   = (const float*)d_in[10];
  const float* blv   = (const float*)d_in[11];
  float* out = (float*)d_out;

  // workspace layout
  float* bufA = (float*)d_ws;                          // [N,H]  h / agg
  float* bufB = bufA + (size_t)N_ * H_;                // [N,H]  m
  float* ge   = bufB + (size_t)N_ * H_;                // [G,H]
  int*   deg  = (int*)(ge + (size_t)G_ * H_);          // [N]    degree / fill cursor
  int*   rowp = deg + N_;                              // [N+1]
  int*   ssrc = rowp + (N_ + 1);                       // [E]    src sorted by dst
  // total ≈ 116.5 MB

  // ---- CSR build (once; edge list shared by all 3 layers) ----
  hipMemsetAsync(deg, 0, (size_t)N_ * sizeof(int), stream);
  k_hist<<<2048, 256, 0, stream>>>(ei, deg);
  k_scan<<<1, 1024, 0, stream>>>(deg, rowp);
  hipMemsetAsync(deg, 0, (size_t)N_ * sizeof(int), stream);   // reuse as fill cursor
  k_fill<<<2048, 256, 0, stream>>>(ei, rowp, deg, ssrc);

  // ---- h = relu(x @ W_in + b_in) ----
  k_input<<<(N_ + 1) / 2, 256, 0, stream>>>(x, Win, bin, bufA);

  for (int l = 0; l < L_; ++l) {
    // m = relu(h) @ W_msg[l] + b_msg[l]
    k_msg<<<512, 512, 0, stream>>>(bufA, Wmsg + (size_t)l * H_ * H_,
                                   bmsg + (size_t)l * H_, bufB);
    // h = relu(gather-sum over in-edges) — no atomics, writes every row once
    k_gather<<<N_ / 2, 256, 0, stream>>>(bufB, rowp, ssrc, bufA);
  }

  // ---- graph pooling (relu idempotent on already-relu'd h) ----
  hipMemsetAsync(ge, 0, (size_t)G_ * H_ * sizeof(float), stream);
  k_pool<<<(N_ + POOL_CHUNK - 1) / POOL_CHUNK, 128, 0, stream>>>(bufA, batch, ge);

  // ---- heads ----
  k_out<<<G_, 128, 0, stream>>>(ge, Wmean, bmean, Wlv, blv, out);
}

// Round 3
// 1138.102 us; speedup vs baseline: 14.9030x; 2.0100x over previous
//
#include <hip/hip_runtime.h>

// Problem constants (fixed by the reference)
constexpr int N_  = 100000;
constexpr int E_  = 3200000;
constexpr int FIN = 16;
constexpr int H_  = 128;
constexpr int LAT = 64;
constexpr int L_  = 3;
constexpr int G_  = 1024;

using bf16x8 = __attribute__((ext_vector_type(8))) short;
using f32x4  = __attribute__((ext_vector_type(4))) float;

__device__ inline float bf2f(unsigned int u) {
  union { unsigned int i; float f; } v; v.i = u << 16; return v.f;
}
__device__ inline unsigned short f2bf(float f) {
  union { float f; unsigned int i; } v; v.f = f;
  unsigned int r = v.i + 0x7fffu + ((v.i >> 16) & 1u);   // RNE
  return (unsigned short)(r >> 16);
}

// ---------------------------------------------------------------------------
// One-time: Wt[l][c][k] = bf16(Wmsg[l][k][c])   (transposed for B-fragments)
// ---------------------------------------------------------------------------
__global__ __launch_bounds__(256) void k_wconv(const float* __restrict__ W,
                                               unsigned short* __restrict__ Wt) {
  const int idx = blockIdx.x * 256 + threadIdx.x;      // over 3*128*128
  if (idx < L_ * H_ * H_) {
    const int l = idx >> 14, rem = idx & 16383;
    const int c = rem >> 7, k = rem & 127;
    Wt[idx] = f2bf(W[l * H_ * H_ + k * H_ + c]);
  }
}

// ---------------------------------------------------------------------------
// h = relu(x @ W_in + b_in) -> bf16.  4 nodes/block, lane owns 2 channels.
// ---------------------------------------------------------------------------
__global__ __launch_bounds__(256) void k_input(const float* __restrict__ x,
                                               const float* __restrict__ Win,
                                               const float* __restrict__ bin,
                                               unsigned short* __restrict__ h) {
  __shared__ float Wl[FIN * H_];   // 8 KB
  __shared__ float xl[4 * FIN];
  const int tid = threadIdx.x;
  for (int i = tid; i < FIN * H_; i += 256) Wl[i] = Win[i];
  const int n0 = blockIdx.x * 4;   // N divisible by 4
  if (tid < 4 * FIN) xl[tid] = x[(size_t)n0 * FIN + tid];
  __syncthreads();
  const int nl = tid >> 6, l = tid & 63;
  float a0 = bin[2 * l], a1 = bin[2 * l + 1];
#pragma unroll
  for (int k = 0; k < FIN; ++k) {
    const float xv = xl[nl * FIN + k];
    a0 += xv * Wl[k * H_ + 2 * l];
    a1 += xv * Wl[k * H_ + 2 * l + 1];
  }
  const unsigned int packed =
      (unsigned int)f2bf(fmaxf(a0, 0.f)) | ((unsigned int)f2bf(fmaxf(a1, 0.f)) << 16);
  *reinterpret_cast<unsigned int*>(h + (size_t)(n0 + nl) * H_ + 2 * l) = packed;
}

// ---------------------------------------------------------------------------
// m = h @ W + b  via MFMA (bf16 in, fp32 acc, bf16 out).
// Block = 256 thr = 4 waves. Block tile: 32 nodes x 128 cols.
// Wave w: cols [w*32, w*32+32); 2 row-tiles x 2 col-tiles x 4 K-steps.
// ---------------------------------------------------------------------------
__global__ __launch_bounds__(256) void k_msg_mfma(const unsigned short* __restrict__ h,
                                                  const unsigned short* __restrict__ Wt,
                                                  const float* __restrict__ b,
                                                  unsigned short* __restrict__ m) {
  const int wave = threadIdx.x >> 6;
  const int lane = threadIdx.x & 63;
  const int r = lane & 15;
  const int g = lane >> 4;               // 0..3
  const int n0 = blockIdx.x * 32;
  const int cb = wave * 32;

  f32x4 acc[2][2] = {};
#pragma unroll
  for (int kk = 0; kk < 4; ++kk) {
    const int k0 = kk * 32;
    const int koff = k0 + g * 8;
    const bf16x8 a0 = *reinterpret_cast<const bf16x8*>(h + (size_t)(n0 + r) * H_ + koff);
    const bf16x8 a1 = *reinterpret_cast<const bf16x8*>(h + (size_t)(n0 + 16 + r) * H_ + koff);
    const bf16x8 b0 = *reinterpret_cast<const bf16x8*>(Wt + (size_t)(cb + r) * H_ + koff);
    const bf16x8 b1 = *reinterpret_cast<const bf16x8*>(Wt + (size_t)(cb + 16 + r) * H_ + koff);
    acc[0][0] = __builtin_amdgcn_mfma_f32_16x16x32_bf16(a0, b0, acc[0][0], 0, 0, 0);
    acc[0][1] = __builtin_amdgcn_mfma_f32_16x16x32_bf16(a0, b1, acc[0][1], 0, 0, 0);
    acc[1][0] = __builtin_amdgcn_mfma_f32_16x16x32_bf16(a1, b0, acc[1][0], 0, 0, 0);
    acc[1][1] = __builtin_amdgcn_mfma_f32_16x16x32_bf16(a1, b1, acc[1][1], 0, 0, 0);
  }

  const float bc0 = b[cb + r];
  const float bc1 = b[cb + 16 + r];
#pragma unroll
  for (int rt = 0; rt < 2; ++rt)
#pragma unroll
    for (int ct = 0; ct < 2; ++ct) {
      const float bc = ct ? bc1 : bc0;
      const int col = cb + ct * 16 + r;
#pragma unroll
      for (int j = 0; j < 4; ++j) {
        const int row = n0 + rt * 16 + g * 4 + j;
        m[(size_t)row * H_ + col] = f2bf(acc[rt][ct][j] + bc);
      }
    }
}

// ---------------------------------------------------------------------------
// CSR build: counting sort of edges by dst (edge list is layer-invariant).
// ---------------------------------------------------------------------------
__global__ __launch_bounds__(256) void k_hist(const int* __restrict__ ei,
                                              int* __restrict__ deg) {
  const int gid = blockIdx.x * blockDim.x + threadIdx.x;
  const int stride = gridDim.x * blockDim.x;
  for (int e = gid; e < E_; e += stride) atomicAdd(&deg[ei[E_ + e]], 1);
}

__global__ __launch_bounds__(1024) void k_scan(const int* __restrict__ deg,
                                               int* __restrict__ rowptr) {
  __shared__ int sums[1024];
  const int t = threadIdx.x;
  constexpr int CH = (N_ + 1023) / 1024;   // 98
  const int beg = t * CH;
  const int end = min(beg + CH, N_);
  int s = 0;
  for (int i = beg; i < end; ++i) s += deg[i];
  sums[t] = s;
  __syncthreads();
  for (int off = 1; off < 1024; off <<= 1) {
    const int add = (t >= off) ? sums[t - off] : 0;
    __syncthreads();
    sums[t] += add;
    __syncthreads();
  }
  int run = (t == 0) ? 0 : sums[t - 1];
  for (int i = beg; i < end; ++i) { rowptr[i] = run; run += deg[i]; }
  if (beg < N_ && end == N_) rowptr[N_] = run;
}

__global__ __launch_bounds__(256) void k_fill(const int* __restrict__ ei,
                                              const int* __restrict__ rowptr,
                                              int* __restrict__ fill,
                                              int* __restrict__ ssrc) {
  const int gid = blockIdx.x * blockDim.x + threadIdx.x;
  const int stride = gridDim.x * blockDim.x;
  for (int e = gid; e < E_; e += stride) {
    const int src = ei[e];
    const int dst = ei[E_ + e];
    const int pos = rowptr[dst] + atomicAdd(&fill[dst], 1);
    ssrc[pos] = src;
  }
}

// ---------------------------------------------------------------------------
// h[n] = relu( sum_{e in CSR[n]} m[ssrc[e]] )  bf16 rows, fp32 accum.
// 64 lanes per node (2 channels each), 4 nodes per 256-thread block.
// ---------------------------------------------------------------------------
__global__ __launch_bounds__(256) void k_gather(const unsigned short* __restrict__ m,
                                                const int* __restrict__ rowptr,
                                                const int* __restrict__ ssrc,
                                                unsigned short* __restrict__ h) {
  const int n = blockIdx.x * 4 + (threadIdx.x >> 6);
  const int c2 = threadIdx.x & 63;          // channel pair -> channels 2c2, 2c2+1
  const int beg = rowptr[n], end = rowptr[n + 1];
  float a0 = 0.f, a1 = 0.f;
  int i = beg;
  for (; i + 1 < end; i += 2) {
    const int s0 = ssrc[i];
    const int s1 = ssrc[i + 1];
    const unsigned int v0 = *reinterpret_cast<const unsigned int*>(m + (size_t)s0 * H_ + 2 * c2);
    const unsigned int v1 = *reinterpret_cast<const unsigned int*>(m + (size_t)s1 * H_ + 2 * c2);
    a0 += bf2f(v0 & 0xffffu);  a1 += bf2f(v0 >> 16);
    a0 += bf2f(v1 & 0xffffu);  a1 += bf2f(v1 >> 16);
  }
  if (i < end) {
    const unsigned int v = *reinterpret_cast<const unsigned int*>(m + (size_t)ssrc[i] * H_ + 2 * c2);
    a0 += bf2f(v & 0xffffu);  a1 += bf2f(v >> 16);
  }
  const unsigned int packed =
      (unsigned int)f2bf(fmaxf(a0, 0.f)) | ((unsigned int)f2bf(fmaxf(a1, 0.f)) << 16);
  *reinterpret_cast<unsigned int*>(h + (size_t)n * H_ + 2 * c2) = packed;
}

// ---------------------------------------------------------------------------
// ge[g] += h[n] (h already post-relu) with batch sorted: running sum + flush.
// ---------------------------------------------------------------------------
constexpr int POOL_CHUNK = 128;
__global__ __launch_bounds__(128) void k_pool(const unsigned short* __restrict__ h,
                                              const int* __restrict__ batch,
                                              float* __restrict__ ge) {
  __shared__ int bl[POOL_CHUNK];
  const int tid = threadIdx.x;
  const int start = blockIdx.x * POOL_CHUNK;
  const int cnt = min(POOL_CHUNK, N_ - start);
  if (tid < cnt) bl[tid] = batch[start + tid];
  __syncthreads();
  float run = 0.f;
  int cur = bl[0];
  for (int i = 0; i < cnt; ++i) {
    const int bid = bl[i];
    const float v = bf2f((unsigned int)h[(size_t)(start + i) * H_ + tid]);
    if (bid != cur) {
      unsafeAtomicAdd(&ge[(size_t)cur * H_ + tid], run);
      run = 0.f;
      cur = bid;
    }
    run += v;
  }
  unsafeAtomicAdd(&ge[(size_t)cur * H_ + tid], run);
}

// ---------------------------------------------------------------------------
// out = [ge @ W_mean + b_mean ; ge @ W_logvar + b_logvar]
// ---------------------------------------------------------------------------
__global__ __launch_bounds__(128) void k_out(const float* __restrict__ ge,
                                             const float* __restrict__ Wm,
                                             const float* __restrict__ bm,
                                             const float* __restrict__ Wv,
                                             const float* __restrict__ bv,
                                             float* __restrict__ out) {
  __shared__ float gl[H_];
  const int g = blockIdx.x, tid = threadIdx.x;
  gl[tid] = ge[(size_t)g * H_ + tid];
  __syncthreads();
  const bool is_mean = (tid < LAT);
  const float* W = is_mean ? Wm : Wv;
  const float* bb = is_mean ? bm : bv;
  const int c = tid & 63;
  float acc = bb[c];
#pragma unroll 8
  for (int k = 0; k < H_; ++k) acc += gl[k] * W[k * LAT + c];
  const size_t off = is_mean ? 0 : (size_t)G_ * LAT;
  out[off + (size_t)g * LAT + c] = acc;
}

// ---------------------------------------------------------------------------
extern "C" void kernel_launch(void* const* d_in, const int* in_sizes, int n_in,
                              void* d_out, int out_size, void* d_ws, size_t ws_size,
                              hipStream_t stream) {
  const float* x     = (const float*)d_in[0];
  const int*   ei    = (const int*)d_in[1];   // [2,E] int32
  const int*   batch = (const int*)d_in[2];   // [N]  int32 (sorted)
  const float* Win   = (const float*)d_in[4];
  const float* bin   = (const float*)d_in[5];
  const float* Wmsg  = (const float*)d_in[6];
  const float* bmsg  = (const float*)d_in[7];
  const float* Wmean = (const float*)d_in[8];
  const float* bmean = (const float*)d_in[9];
  const float* Wlv   = (const float*)d_in[10];
  const float* blv   = (const float*)d_in[11];
  float* out = (float*)d_out;

  // workspace layout (bytes)
  char* p = (char*)d_ws;
  unsigned short* h  = (unsigned short*)p;  p += (size_t)N_ * H_ * 2;   // 25.6 MB
  unsigned short* m  = (unsigned short*)p;  p += (size_t)N_ * H_ * 2;   // 25.6 MB
  unsigned short* Wt = (unsigned short*)p;  p += (size_t)L_ * H_ * H_ * 2;
  float* ge          = (float*)p;           p += (size_t)G_ * H_ * 4;
  int* deg           = (int*)p;             p += (size_t)N_ * 4;
  int* rowp          = (int*)p;             p += (size_t)(N_ + 1) * 4;
  int* ssrc          = (int*)p;             // [E]

  // ---- one-time weight convert+transpose ----
  k_wconv<<<(L_ * H_ * H_ + 255) / 256, 256, 0, stream>>>(Wmsg, Wt);

  // ---- CSR build (once; edge list shared by all 3 layers) ----
  hipMemsetAsync(deg, 0, (size_t)N_ * sizeof(int), stream);
  k_hist<<<2048, 256, 0, stream>>>(ei, deg);
  k_scan<<<1, 1024, 0, stream>>>(deg, rowp);
  hipMemsetAsync(deg, 0, (size_t)N_ * sizeof(int), stream);   // reuse as fill cursor
  k_fill<<<2048, 256, 0, stream>>>(ei, rowp, deg, ssrc);

  // ---- h = relu(x @ W_in + b_in) ----
  k_input<<<N_ / 4, 256, 0, stream>>>(x, Win, bin, h);

  for (int l = 0; l < L_; ++l) {
    k_msg_mfma<<<N_ / 32, 256, 0, stream>>>(h, Wt + (size_t)l * H_ * H_,
                                            bmsg + (size_t)l * H_, m);
    k_gather<<<N_ / 4, 256, 0, stream>>>(m, rowp, ssrc, h);
  }

  // ---- graph pooling ----
  hipMemsetAsync(ge, 0, (size_t)G_ * H_ * sizeof(float), stream);
  k_pool<<<(N_ + POOL_CHUNK - 1) / POOL_CHUNK, 128, 0, stream>>>(h, batch, ge);

  // ---- heads ----
  k_out<<<G_, 128, 0, stream>>>(ge, Wmean, bmean, Wlv, blv, out);
}